// Round 10
// baseline (167.744 us; speedup 1.0000x reference)
//
#include <hip/hip_runtime.h>

#define C_DIM 256
#define NCODE 1024
#define MARGIN 0.02f

typedef __bf16 bf16x8 __attribute__((ext_vector_type(8)));
typedef float f32x4 __attribute__((ext_vector_type(4)));

// ws layout (byte offsets)
#define WS_ENORM 0         // f32[1024]
#define WS_META  4096      // u32 rescue count
#define WS_RLIST 8192      // u32[32768]
#define WS_BP    139264    // u16[1024][512]  [eh|el]  (1 MB)
#define WS_PB    1187840   // float2[32768][4] (b1,b2) per (row, ntile)
#define WS_PBI   2236416   // u32[32768][4]

#define GLOAD_LDS16(g, s)                                                            \
  __builtin_amdgcn_global_load_lds(                                                  \
      (const __attribute__((address_space(1))) unsigned int*)(g),                    \
      (__attribute__((address_space(3))) unsigned int*)(s), 16, 0, 0)

__device__ __forceinline__ void bf16split(float x, unsigned short& h, unsigned short& l) {
    unsigned u  = __float_as_uint(x);
    unsigned rh = (u + 0x7FFFu + ((u >> 16) & 1u)) & 0xFFFF0000u;   // RNE to bf16
    float    lf = x - __uint_as_float(rh);                          // exact
    unsigned ul = __float_as_uint(lf);
    h = (unsigned short)(rh >> 16);
    l = (unsigned short)((ul + 0x7FFFu + ((ul >> 16) & 1u)) >> 16);
}

// ---------- prep_misc: enorm (fp32 wave-reduce) + meta reset ----------
__global__ __launch_bounds__(256) void prep_misc_kernel(const float* __restrict__ emb,
                                                        float* __restrict__ enorm,
                                                        unsigned* __restrict__ meta) {
    int gid = blockIdx.x * 256 + threadIdx.x;
    if (gid == 0) meta[0] = 0u;
    int row = gid >> 6, lane = gid & 63;
    float4 v = reinterpret_cast<const float4*>(emb)[(size_t)row * 64 + lane];
    float s = v.x * v.x + v.y * v.y + v.z * v.z + v.w * v.w;
    #pragma unroll
    for (int off = 32; off; off >>= 1) s += __shfl_xor(s, off, 64);
    if (lane == 0) enorm[row] = s;
}

// ---------- prep_split: rows of fp32 -> u16 [hi(256) | lo(256)] bf16 ----------
__global__ __launch_bounds__(256) void prep_split_kernel(const float* __restrict__ src,
                                                         unsigned short* __restrict__ dst) {
    int gid = blockIdx.x * 256 + threadIdx.x;   // rows*32
    int row = gid >> 5, seg = gid & 31;
    const float* s = src + (size_t)row * 256 + seg * 8;
    float4 v0 = *reinterpret_cast<const float4*>(s);
    float4 v1 = *reinterpret_cast<const float4*>(s + 4);
    float vs[8] = {v0.x, v0.y, v0.z, v0.w, v1.x, v1.y, v1.z, v1.w};
    unsigned short h[8], l[8];
    #pragma unroll
    for (int j = 0; j < 8; ++j) bf16split(vs[j], h[j], l[j]);
    uint4 hp, lp;
    hp.x = (unsigned)h[0] | ((unsigned)h[1] << 16);
    hp.y = (unsigned)h[2] | ((unsigned)h[3] << 16);
    hp.z = (unsigned)h[4] | ((unsigned)h[5] << 16);
    hp.w = (unsigned)h[6] | ((unsigned)h[7] << 16);
    lp.x = (unsigned)l[0] | ((unsigned)l[1] << 16);
    lp.y = (unsigned)l[2] | ((unsigned)l[3] << 16);
    lp.z = (unsigned)l[4] | ((unsigned)l[5] << 16);
    lp.w = (unsigned)l[6] | ((unsigned)l[7] << 16);
    *reinterpret_cast<uint4*>(dst + (size_t)row * 512 + seg * 8)       = hp;
    *reinterpret_cast<uint4*>(dst + (size_t)row * 512 + 256 + seg * 8) = lp;
}

// K-step -> source column maps (K'=768 = zh*eh | zh*el | zl*eh)
#define ACOL(ks) ((((ks) & 3) << 6) + ((ks) >= 8 ? 256 : 0))
#define BCOL(ks) ((((ks) & 3) << 6) + (((ks) >= 4 && (ks) < 8) ? 256 : 0))

// ---------- main: 256x256 8-phase bf16 3-pass GEMM + top-2 epilogue ----------
// grid 512 = 128 m-tiles x 4 n-tiles; 512 thr = 8 waves (2M x 4N).
// LDS frag-order: buf(2) x half(2) x 8 slot-pairs x 1024 u16 per matrix.
__global__ __launch_bounds__(512, 2) void vq_gemm8_kernel(
    const unsigned short* __restrict__ ap, const unsigned short* __restrict__ bp,
    const float* __restrict__ enorm, float2* __restrict__ pb,
    unsigned* __restrict__ pbi) {
    __shared__ unsigned short AbU[32768];   // 64 KB
    __shared__ unsigned short BbU[32768];   // 64 KB
    __shared__ float en_s[256];

    const int t = threadIdx.x;
    const int w = t >> 6, lane = t & 63;
    const int lr = lane & 15, lg = lane >> 4;
    const int wm = w >> 2, wn = w & 3;
    const int bid = blockIdx.x;
    const long r0 = (long)(bid >> 2) * 256;
    const int  c0 = (bid & 3) * 256;

    if (t < 256) en_s[t] = enorm[c0 + t];

    // per-lane global source ptrs (row from lr, col-group from lg)
    const unsigned short* AsrcL = ap + (size_t)(r0 + w * 16 + lr) * 512 + lg * 8;
    const unsigned short* BsrcL = bp + (size_t)(c0 + w * 16 + lr) * 512 + lg * 8;
    // wave-uniform stage dest bases (u16 offsets); wave w fills slot-pair w
    unsigned short* AstW = AbU + w * 1024;
    unsigned short* BstW = BbU + w * 1024;
    // per-lane read bases [buf]  (N-wave wn: half = wn>>1, 4 slot-pairs at (wn&1)*4096)
    const unsigned short* Ard[2] = {AbU + wm * 8192 + lane * 8,
                                    AbU + 16384 + wm * 8192 + lane * 8};
    const unsigned short* Brd[2] = {BbU + (wn >> 1) * 8192 + (wn & 1) * 4096 + lane * 8,
                                    BbU + 16384 + (wn >> 1) * 8192 + (wn & 1) * 4096 + lane * 8};

#define STG_A(bf, h, col) {                                                          \
    GLOAD_LDS16(AsrcL + (h) * 65536 + (col),      AstW + (bf) * 16384 + (h) * 8192); \
    GLOAD_LDS16(AsrcL + (h) * 65536 + (col) + 32, AstW + (bf) * 16384 + (h) * 8192 + 512); }
#define STG_B(bf, h, col) {                                                          \
    GLOAD_LDS16(BsrcL + (h) * 65536 + (col),      BstW + (bf) * 16384 + (h) * 8192); \
    GLOAD_LDS16(BsrcL + (h) * 65536 + (col) + 32, BstW + (bf) * 16384 + (h) * 8192 + 512); }
#define RD_A(AR, BUF, MB) {                                                          \
    _Pragma("unroll") for (int mf = 0; mf < 4; ++mf)                                 \
      _Pragma("unroll") for (int kc = 0; kc < 2; ++kc)                               \
        AR[mf * 2 + kc] = *reinterpret_cast<const bf16x8*>(                          \
            Ard[BUF] + ((MB) + mf) * 1024 + kc * 512); }
#define RD_B(BUF, NB) {                                                              \
    _Pragma("unroll") for (int nf = 0; nf < 2; ++nf)                                 \
      _Pragma("unroll") for (int kc = 0; kc < 2; ++kc)                               \
        Breg[nf * 2 + kc] = *reinterpret_cast<const bf16x8*>(                        \
            Brd[BUF] + ((NB) + nf) * 1024 + kc * 512); }
#define DO_MFMA(AR, MB, NB) {                                                        \
    _Pragma("unroll") for (int mf = 0; mf < 4; ++mf)                                 \
      _Pragma("unroll") for (int nf = 0; nf < 2; ++nf) {                             \
        acc[(MB) + mf][(NB) + nf] = __builtin_amdgcn_mfma_f32_16x16x32_bf16(         \
            AR[mf * 2 + 0], Breg[nf * 2 + 0], acc[(MB) + mf][(NB) + nf], 0, 0, 0);   \
        acc[(MB) + mf][(NB) + nf] = __builtin_amdgcn_mfma_f32_16x16x32_bf16(         \
            AR[mf * 2 + 1], Breg[nf * 2 + 1], acc[(MB) + mf][(NB) + nf], 0, 0, 0); } }
#define BAR()  __builtin_amdgcn_s_barrier()
#define LGKM0() asm volatile("s_waitcnt lgkmcnt(0)" ::: "memory")
#define PRIO(x) __builtin_amdgcn_s_setprio(x)

    f32x4 acc[8][4];
    #pragma unroll
    for (int mf = 0; mf < 8; ++mf)
        #pragma unroll
        for (int nf = 0; nf < 4; ++nf) acc[mf][nf] = (f32x4){0.f, 0.f, 0.f, 0.f};

    // prologue: stage A(0)h01, B(0)h01, A(1)h01; keep A(1) in flight
    {
        const int a0 = ACOL(0), b0 = BCOL(0), a1 = ACOL(1);
        STG_A(0, 0, a0); STG_A(0, 1, a0);
        STG_B(0, 0, b0); STG_B(0, 1, b0);
        STG_A(1, 0, a1); STG_A(1, 1, a1);
        asm volatile("s_waitcnt vmcnt(4)" ::: "memory");
        BAR();
    }

    bf16x8 Alo[8], Ahi[8], Breg[4];

    #pragma unroll 1
    for (int it = 0; it < 6; ++it) {
        const bool pre = it < 5;
        const int cBb  = BCOL(2 * it + 1);
        const int cAa2 = pre ? ACOL(2 * it + 2) : 0;
        const int cBa2 = pre ? BCOL(2 * it + 2) : 0;
        const int cAb2 = pre ? ACOL(2 * it + 3) : 0;

        // ---- K-step a (buf 0) ----
        RD_A(Alo, 0, 0); RD_B(0, 0);
        STG_B(1, 0, cBb);
        BAR(); LGKM0(); PRIO(1); DO_MFMA(Alo, 0, 0); PRIO(0); BAR();

        RD_A(Ahi, 0, 4);
        STG_B(1, 1, cBb);
        BAR(); LGKM0(); PRIO(1); DO_MFMA(Ahi, 4, 0); PRIO(0); BAR();

        RD_B(0, 2);
        if (pre) STG_A(0, 0, cAa2);
        BAR(); LGKM0(); PRIO(1); DO_MFMA(Alo, 0, 2); PRIO(0); BAR();

        if (pre) STG_A(0, 1, cAa2);
        BAR(); PRIO(1); DO_MFMA(Ahi, 4, 2); PRIO(0);
        if (pre) { asm volatile("s_waitcnt vmcnt(4)" ::: "memory"); }
        else     { asm volatile("s_waitcnt vmcnt(0)" ::: "memory"); }
        BAR();

        // ---- K-step b (buf 1) ----
        RD_A(Alo, 1, 0); RD_B(1, 0);
        if (pre) STG_B(0, 0, cBa2);
        BAR(); LGKM0(); PRIO(1); DO_MFMA(Alo, 0, 0); PRIO(0); BAR();

        RD_A(Ahi, 1, 4);
        if (pre) STG_B(0, 1, cBa2);
        BAR(); LGKM0(); PRIO(1); DO_MFMA(Ahi, 4, 0); PRIO(0); BAR();

        RD_B(1, 2);
        if (pre) STG_A(1, 0, cAb2);
        BAR(); LGKM0(); PRIO(1); DO_MFMA(Alo, 0, 2); PRIO(0); BAR();

        if (pre) STG_A(1, 1, cAb2);
        BAR(); PRIO(1); DO_MFMA(Ahi, 4, 2); PRIO(0);
        if (pre) { asm volatile("s_waitcnt vmcnt(4)" ::: "memory"); }
        BAR();
    }

    // ---- epilogue: d = en - 2*acc, top-2, merge ----
    __syncthreads();
    float* mv1 = reinterpret_cast<float*>(AbU);   // [256][4]
    float* mv2 = mv1 + 1024;
    int*   mi  = reinterpret_cast<int*>(BbU);     // [256][4]

    #pragma unroll
    for (int mf = 0; mf < 8; ++mf) {
        #pragma unroll
        for (int r = 0; r < 4; ++r) {
            float b1 = 3.4e38f, b2 = 3.4e38f; int i1 = 0;
            #pragma unroll
            for (int nf = 0; nf < 4; ++nf) {   // ascending codes per lane
                int cl = wn * 64 + nf * 16 + lr;
                float d = fmaf(-2.f, acc[mf][nf][r], en_s[cl]);
                if (d < b1) { b2 = b1; b1 = d; i1 = c0 + cl; }
                else if (d < b2) { b2 = d; }
            }
            #pragma unroll
            for (int off = 8; off; off >>= 1) {
                float ob1 = __shfl_xor(b1, off, 64);
                float ob2 = __shfl_xor(b2, off, 64);
                int   oi1 = __shfl_xor(i1, off, 64);
                if (ob1 < b1 || (ob1 == b1 && oi1 < i1)) {
                    b2 = fminf(b1, ob2); b1 = ob1; i1 = oi1;
                } else {
                    b2 = fminf(b2, ob1);
                }
            }
            if (lr == 0) {
                int rowl = wm * 128 + mf * 16 + lg * 4 + r;
                mv1[rowl * 4 + wn] = b1; mv2[rowl * 4 + wn] = b2; mi[rowl * 4 + wn] = i1;
            }
        }
    }
    __syncthreads();
    if (t < 256) {
        float B1 = 3.4e38f, B2 = 3.4e38f; int I1 = 0;
        #pragma unroll
        for (int s = 0; s < 4; ++s) {   // ascending wn = ascending codes
            float v1 = mv1[t * 4 + s], v2 = mv2[t * 4 + s]; int j = mi[t * 4 + s];
            if (v1 < B1) { B2 = fminf(B1, v2); B1 = v1; I1 = j; }
            else         { B2 = fminf(B2, v1); }
        }
        pb [(r0 + t) * 4 + (bid & 3)] = make_float2(B1, B2);
        pbi[(r0 + t) * 4 + (bid & 3)] = (unsigned)I1;
    }
}

// ---------- finalize+gather: merge 4 n-tile slots, idx, rescue-flag, z_q ----------
__global__ __launch_bounds__(256) void finalize_gather_kernel(
    const float* __restrict__ emb, const float2* __restrict__ pb,
    const unsigned* __restrict__ pbi, float* __restrict__ zq,
    float* __restrict__ idx_out, unsigned* __restrict__ meta,
    unsigned* __restrict__ rlist) {
    const long row = (long)blockIdx.x * 4 + (threadIdx.x >> 6);
    const int lane = threadIdx.x & 63;
    float B1 = 3.4e38f, B2 = 3.4e38f; unsigned I1 = 0;
    #pragma unroll
    for (int s = 0; s < 4; ++s) {   // ascending n-tile = ascending codes
        float2   p = pb [row * 4 + s];
        unsigned j = pbi[row * 4 + s];
        if (p.x < B1) { B2 = fminf(B1, p.y); B1 = p.x; I1 = j; }
        else          { B2 = fminf(B2, p.x); }
    }
    if (lane == 0) {
        idx_out[row] = (float)I1;
        if (B2 - B1 <= MARGIN) rlist[atomicAdd(meta, 1u)] = (unsigned)row;
    }
    float4 v = reinterpret_cast<const float4*>(emb)[(size_t)I1 * 64 + lane];
    reinterpret_cast<float4*>(zq)[row * 64 + lane] = v;
}

// ---------- rescue: exact fp32 argmin for flagged rows; writes z_q+idx ----------
__global__ __launch_bounds__(256) void rescue_kernel(
    const float* __restrict__ z, const float* __restrict__ emb,
    const float* __restrict__ enorm, const unsigned* __restrict__ meta,
    const unsigned* __restrict__ rlist, float* __restrict__ zq,
    float* __restrict__ idx_out) {
    __shared__ float zrow[C_DIM];
    __shared__ float rd[256];
    __shared__ unsigned rix[256];
    const unsigned cnt = meta[0];
    for (unsigned li = blockIdx.x; li < cnt; li += gridDim.x) {
        unsigned row = rlist[li];
        __syncthreads();
        if (threadIdx.x < 64) {
            float4 v = reinterpret_cast<const float4*>(z)[(size_t)row * 64 + threadIdx.x];
            reinterpret_cast<float4*>(zrow)[threadIdx.x] = v;
        }
        __syncthreads();
        const int c = threadIdx.x;
        float a0 = 0.f, a1 = 0.f, a2 = 0.f, a3 = 0.f;
        const float4* zp = reinterpret_cast<const float4*>(zrow);
        const float4* e0 = reinterpret_cast<const float4*>(emb + (size_t)(c)       * C_DIM);
        const float4* e1 = reinterpret_cast<const float4*>(emb + (size_t)(c + 256) * C_DIM);
        const float4* e2 = reinterpret_cast<const float4*>(emb + (size_t)(c + 512) * C_DIM);
        const float4* e3 = reinterpret_cast<const float4*>(emb + (size_t)(c + 768) * C_DIM);
        #pragma unroll 8
        for (int k = 0; k < 64; ++k) {
            float4 z4 = zp[k];
            float4 f0 = e0[k], f1 = e1[k], f2 = e2[k], f3 = e3[k];
            a0 = fmaf(z4.x, f0.x, a0); a0 = fmaf(z4.y, f0.y, a0);
            a0 = fmaf(z4.z, f0.z, a0); a0 = fmaf(z4.w, f0.w, a0);
            a1 = fmaf(z4.x, f1.x, a1); a1 = fmaf(z4.y, f1.y, a1);
            a1 = fmaf(z4.z, f1.z, a1); a1 = fmaf(z4.w, f1.w, a1);
            a2 = fmaf(z4.x, f2.x, a2); a2 = fmaf(z4.y, f2.y, a2);
            a2 = fmaf(z4.z, f2.z, a2); a2 = fmaf(z4.w, f2.w, a2);
            a3 = fmaf(z4.x, f3.x, a3); a3 = fmaf(z4.y, f3.y, a3);
            a3 = fmaf(z4.z, f3.z, a3); a3 = fmaf(z4.w, f3.w, a3);
        }
        float d0 = fmaf(-2.f, a0, enorm[c]);
        float d1 = fmaf(-2.f, a1, enorm[c + 256]);
        float d2 = fmaf(-2.f, a2, enorm[c + 512]);
        float d3 = fmaf(-2.f, a3, enorm[c + 768]);
        float bd = d0; unsigned bi = (unsigned)c;
        if (d1 < bd) { bd = d1; bi = (unsigned)(c + 256); }
        if (d2 < bd) { bd = d2; bi = (unsigned)(c + 512); }
        if (d3 < bd) { bd = d3; bi = (unsigned)(c + 768); }
        rd[threadIdx.x] = bd; rix[threadIdx.x] = bi;
        __syncthreads();
        for (int s = 128; s; s >>= 1) {
            if (threadIdx.x < (unsigned)s) {
                float od = rd[threadIdx.x + s]; unsigned oi = rix[threadIdx.x + s];
                if (od < rd[threadIdx.x] ||
                    (od == rd[threadIdx.x] && oi < rix[threadIdx.x])) {
                    rd[threadIdx.x] = od; rix[threadIdx.x] = oi;
                }
            }
            __syncthreads();
        }
        unsigned code = rix[0];
        if (threadIdx.x < 64) {
            float4 v = reinterpret_cast<const float4*>(emb)[(size_t)code * 64 + threadIdx.x];
            reinterpret_cast<float4*>(zq)[(size_t)row * 64 + threadIdx.x] = v;
        }
        if (threadIdx.x == 0) idx_out[row] = (float)code;
    }
}

extern "C" void kernel_launch(void* const* d_in, const int* in_sizes, int n_in,
                              void* d_out, int out_size, void* d_ws, size_t ws_size,
                              hipStream_t stream) {
    const float* z   = (const float*)d_in[0];
    const float* emb = (const float*)d_in[1];
    const int n = in_sizes[0] / C_DIM;   // 32768

    float* zq      = (float*)d_out;
    float* idx_out = zq + (size_t)n * C_DIM;

    char* ws = (char*)d_ws;
    float*          enorm = (float*)(ws + WS_ENORM);
    unsigned*       meta  = (unsigned*)(ws + WS_META);
    unsigned*       rlist = (unsigned*)(ws + WS_RLIST);
    unsigned short* bp    = (unsigned short*)(ws + WS_BP);
    float2*         pb    = (float2*)(ws + WS_PB);
    unsigned*       pbi   = (unsigned*)(ws + WS_PBI);

    // A' (32768 x 512 u16 = 33.55 MB) aliases z_q output region; fully
    // consumed by vq_gemm8 before finalize/rescue overwrite it.
    unsigned short* ap = (unsigned short*)d_out;

    prep_misc_kernel<<<256, 256, 0, stream>>>(emb, enorm, meta);
    prep_split_kernel<<<128, 256, 0, stream>>>(emb, bp);       // 1024 rows
    prep_split_kernel<<<4096, 256, 0, stream>>>(z, ap);        // 32768 rows
    vq_gemm8_kernel<<<512, 512, 0, stream>>>(ap, bp, enorm, pb, pbi);
    finalize_gather_kernel<<<n / 4, 256, 0, stream>>>(emb, pb, pbi, zq, idx_out,
                                                      meta, rlist);
    rescue_kernel<<<256, 256, 0, stream>>>(z, emb, enorm, meta, rlist, zq, idx_out);
}